// Round 9
// baseline (248.026 us; speedup 1.0000x reference)
//
#include <hip/hip_runtime.h>
#include <cstdint>
#include <cstddef>

#define B_ 2
#define S_ 2049
#define E_ 512
#define H_ 8
#define WIN_ 1024
#define MROWS (B_*S_)     // 4098
#define SP_ 2176          // padded seq for vT cols
#define GBUFN 4104
#define BHS_ (B_*H_*S_)   // 32784

typedef unsigned short ushort_t;
typedef __attribute__((ext_vector_type(8))) short bf16x8;   // 8 bf16 (4 VGPRs)
typedef __attribute__((ext_vector_type(4))) float f32x4;

#define MFMA16(a,b,c) __builtin_amdgcn_mfma_f32_16x16x32_bf16(a,b,c,0,0,0)

__device__ __forceinline__ ushort_t f2bf(float f) {          // RNE fp32->bf16
  unsigned int u = __float_as_uint(f);
  u += 0x7fffu + ((u >> 16) & 1u);
  return (ushort_t)(u >> 16);
}
__device__ __forceinline__ float bf2f(ushort_t h) {
  return __uint_as_float(((unsigned int)h) << 16);
}

// ---------------------------------------------------------------------------
// W [k][n] fp32 -> Wt [n][k] bf16 (z<3: Wq/Wk/Wv; z==3: Wo -> WoHi).
// z==3 blocks also zero the gate accumulators (replaces memset launch).
// ---------------------------------------------------------------------------
__global__ __launch_bounds__(256) void convert_w_kernel(
    const float* __restrict__ W0, const float* __restrict__ W1,
    const float* __restrict__ W2, const float* __restrict__ W3,
    ushort_t* __restrict__ Wt_all, ushort_t* __restrict__ WoHi,
    float* __restrict__ gacc)
{
  __shared__ float tile[32][33];
  int z = blockIdx.z;
  if (z == 3) {
    int gz = (blockIdx.x * 16 + blockIdx.y) * 256 + threadIdx.x;
    if (gz < 2 * GBUFN) gacc[gz] = 0.f;
  }
  const float* W = (z == 0) ? W0 : (z == 1) ? W1 : (z == 2) ? W2 : W3;
  int k0 = blockIdx.x * 32, n0 = blockIdx.y * 32;
  int r = threadIdx.x >> 5, c = threadIdx.x & 31;
#pragma unroll
  for (int i = 0; i < 4; ++i) {
    int rr = r + i * 8;
    tile[rr][c] = W[(size_t)(k0 + rr) * E_ + n0 + c];
  }
  __syncthreads();
#pragma unroll
  for (int i = 0; i < 4; ++i) {
    int rr = r + i * 8;
    float v = tile[c][rr];                       // = W[k0+c][n0+rr]
    size_t dst = (size_t)(n0 + rr) * E_ + k0 + c;
    if (z < 3) Wt_all[(size_t)z * E_ * E_ + dst] = f2bf(v);
    else       WoHi[dst] = f2bf(v);
  }
}

// ---------------------------------------------------------------------------
// QKV projection, 64x128 tile, 2x2 waves (32x64 each), BK=64 (16 barriers),
// reg-prefetch, x fp32 read directly. Per-b m-tiling (grid.x=66).
// z<2: row-major bf16 + fused gate dots. z==2: LDS-transpose -> coalesced vT.
// ---------------------------------------------------------------------------
__global__ __launch_bounds__(256) void gemm_qkv_kernel(
    const float* __restrict__ x, const ushort_t* __restrict__ Wt_all,
    const float* __restrict__ bq, const float* __restrict__ bk,
    const float* __restrict__ bv, const float* __restrict__ wg,
    ushort_t* __restrict__ qkb, ushort_t* __restrict__ vT,
    float* __restrict__ gacc)
{
  __shared__ __align__(16) ushort_t As[64][72];
  __shared__ __align__(16) ushort_t Bs[128][72];
  int tid = threadIdx.x;
  int lane = tid & 63, w = tid >> 6;
  int l15 = lane & 15, quad = lane >> 4;
  int wm = (w & 1) * 32, wn = (w >> 1) * 64;
  int z = blockIdx.z;
  const ushort_t* Wt = Wt_all + (size_t)z * E_ * E_;
  const float* bias = (z == 0) ? bq : (z == 1) ? bk : bv;
  int bt = blockIdx.x;               // 0..65; 33 i-tiles per batch
  int bg2 = bt / 33;
  int bm = (bt - bg2 * 33) * 64;
  int bn = blockIdx.y * 128;
  size_t rowbase = (size_t)bg2 * S_;

  int ar = tid >> 2, acq = (tid & 3) * 16;       // A: 16 fp32 per thread
  int ai = bm + ar; if (ai >= S_) ai = S_ - 1;
  const float* ap = x + (rowbase + ai) * E_ + acq;
  int br = tid >> 1, bcq = (tid & 1) * 32;       // B: 32 bf16 per thread
  const ushort_t* bp = Wt + (size_t)(bn + br) * E_ + bcq;

  const f32x4 fz = {0.f, 0.f, 0.f, 0.f};
  f32x4 acc[2][4];
#pragma unroll
  for (int mt = 0; mt < 2; ++mt)
#pragma unroll
    for (int nt = 0; nt < 4; ++nt) acc[mt][nt] = fz;

  float4 pa[4]; int4 pb[4];
#pragma unroll
  for (int t = 0; t < 4; ++t) { pa[t] = *(const float4*)(ap + t * 4); pb[t] = *(const int4*)(bp + t * 8); }

  for (int k0 = 0; k0 < E_; k0 += 64) {
    __syncthreads();
    int kn = (k0 + 64 < E_) ? (k0 + 64) : k0;
    float4 na[4]; int4 nb[4];
#pragma unroll
    for (int t = 0; t < 4; ++t) { na[t] = *(const float4*)(ap + kn + t * 4); nb[t] = *(const int4*)(bp + kn + t * 8); }
    union { int4 v[2]; ushort_t u[16]; } cv;
#pragma unroll
    for (int t = 0; t < 4; ++t) {
      cv.u[t*4+0] = f2bf(pa[t].x); cv.u[t*4+1] = f2bf(pa[t].y);
      cv.u[t*4+2] = f2bf(pa[t].z); cv.u[t*4+3] = f2bf(pa[t].w);
    }
    *(int4*)&As[ar][acq] = cv.v[0]; *(int4*)&As[ar][acq + 8] = cv.v[1];
#pragma unroll
    for (int t = 0; t < 4; ++t) *(int4*)&Bs[br][bcq + t * 8] = pb[t];
    __syncthreads();
#pragma unroll
    for (int half = 0; half < 2; ++half) {
      bf16x8 a[2], bfr[4];
#pragma unroll
      for (int mt = 0; mt < 2; ++mt) a[mt] = *(const bf16x8*)&As[wm + mt * 16 + l15][half * 32 + quad * 8];
#pragma unroll
      for (int nt = 0; nt < 4; ++nt) bfr[nt] = *(const bf16x8*)&Bs[wn + nt * 16 + l15][half * 32 + quad * 8];
#pragma unroll
      for (int mt = 0; mt < 2; ++mt)
#pragma unroll
        for (int nt = 0; nt < 4; ++nt)
          acc[mt][nt] = MFMA16(a[mt], bfr[nt], acc[mt][nt]);
    }
#pragma unroll
    for (int t = 0; t < 4; ++t) { pa[t] = na[t]; pb[t] = nb[t]; }
  }

  float bb[4];
#pragma unroll
  for (int nt = 0; nt < 4; ++nt) bb[nt] = bias[bn + wn + nt * 16 + l15];

  if (z < 2) {
    ushort_t* C = qkb + (size_t)z * MROWS * E_;
#pragma unroll
    for (int mt = 0; mt < 2; ++mt)
#pragma unroll
      for (int nt = 0; nt < 4; ++nt)
#pragma unroll
        for (int r = 0; r < 4; ++r) {
          int i = bm + wm + mt * 16 + quad * 4 + r;
          if (i < S_)
            C[(rowbase + i) * E_ + bn + wn + nt * 16 + l15] = f2bf(acc[mt][nt][r] + bb[nt]);
        }
    // fused gate partial dots
    const float* wgp = wg + (size_t)z * E_;
    float wv[4];
#pragma unroll
    for (int nt = 0; nt < 4; ++nt) wv[nt] = wgp[bn + wn + nt * 16 + l15];
    float* gp = gacc + (size_t)z * GBUFN;
#pragma unroll
    for (int mt = 0; mt < 2; ++mt)
#pragma unroll
      for (int r = 0; r < 4; ++r) {
        float s = 0.f;
#pragma unroll
        for (int nt = 0; nt < 4; ++nt) s = fmaf(acc[mt][nt][r] + bb[nt], wv[nt], s);
        s += __shfl_xor(s, 1, 16); s += __shfl_xor(s, 2, 16);
        s += __shfl_xor(s, 4, 16); s += __shfl_xor(s, 8, 16);
        int i = bm + wm + mt * 16 + quad * 4 + r;
        if (l15 == 0 && i < S_) atomicAdd(&gp[rowbase + i], s);
      }
  } else {
    // v: LDS transpose (2-way conflicts = free) then coalesced aligned int4
    ushort_t* lt = &Bs[0][0];                    // 64d x 72i tile
    int ti = tid >> 2, tc = (tid & 3) * 16;
#pragma unroll
    for (int hh = 0; hh < 2; ++hh) {
      __syncthreads();
      if ((w >> 1) == hh) {
#pragma unroll
        for (int mt = 0; mt < 2; ++mt)
#pragma unroll
          for (int nt = 0; nt < 4; ++nt) {
            int d = nt * 16 + l15;
#pragma unroll
            for (int r = 0; r < 4; ++r) {
              int il = wm + mt * 16 + quad * 4 + r;
              lt[d * 72 + il] = f2bf(acc[mt][nt][r] + bb[nt]);
            }
          }
      }
      __syncthreads();
      int hg = (bn >> 6) + hh;
      union { int4 q[2]; ushort_t u[16]; } tv;
      tv.q[0] = *(const int4*)&lt[ti * 72 + tc];
      tv.q[1] = *(const int4*)&lt[ti * 72 + tc + 8];
      size_t vrow = ((size_t)(bg2 * H_ + hg) * 64 + ti) * SP_;
#pragma unroll
      for (int c8 = 0; c8 < 2; ++c8) {
        int i2 = bm + tc + c8 * 8;
        if (i2 + 7 < S_) {
          *(int4*)&vT[vrow + i2] = tv.q[c8];
        } else {
#pragma unroll
          for (int e = 0; e < 8; ++e)
            if (i2 + e < S_) vT[vrow + i2 + e] = tv.u[c8 * 8 + e];
        }
      }
    }
  }
}

// ---------------------------------------------------------------------------
// MFMA flash attention, S^T form, fixed-reference softmax, thirds split.
// V B-fragments read DIRECT from global vT (L2-resident; layout matches the
// MFMA B-operand exactly) -> no Vt LDS buffer: 21.3KB LDS, 7 blocks/CU.
// Q pre-scaled by 0.125*log2e; p = exp2(...) (raw v_exp, no mul).
// ---------------------------------------------------------------------------
__global__ __launch_bounds__(256) void attn_kernel(
    const ushort_t* __restrict__ qb, const ushort_t* __restrict__ kb,
    const ushort_t* __restrict__ vT, const float* __restrict__ gq_raw,
    const float* __restrict__ gk_raw, const float* __restrict__ bgate,
    float* __restrict__ Opart, float* __restrict__ Lpart)
{
  __shared__ __align__(16) ushort_t Ks[64][72];    // [j][d]
  __shared__ __align__(16) ushort_t Ps[4][16][72]; // per-wave P [i][j]
  __shared__ float gbs[704];

  int tid = threadIdx.x;
  int lane = tid & 63, w = tid >> 6;
  int l15 = lane & 15, quad = lane >> 4;

  // middle-out q-tile order; 48 blocks (16 bh x 3 thirds) per qt
  int sub = blockIdx.x % 48;
  int qidx = blockIdx.x / 48;
  int off = (qidx + 1) >> 1;
  int qt = 16 + ((qidx & 1) ? -off : off);          // 0..32
  int bh = sub & 15, third = sub >> 4;
  int h = bh & 7, b = bh >> 3;
  int i0 = qt * 64;
  const float LOG2E = 1.44269504f;
  const float coef2 = (-0.5f / (512.f * 512.f)) * LOG2E;
  const float QSC = 0.125f * LOG2E;

  // per-thread q-row
  int i = i0 + w * 16 + l15;
  int ic = (i < S_) ? i : S_ - 1;
  bf16x8 qf0 = *(const bf16x8*)&qb[((size_t)(b * S_ + ic)) * E_ + h * 64 + quad * 8];
  bf16x8 qf1 = *(const bf16x8*)&qb[((size_t)(b * S_ + ic)) * E_ + h * 64 + 32 + quad * 8];
#pragma unroll
  for (int e = 0; e < 8; ++e) {                     // fold D^-0.5 * log2e into Q
    qf0[e] = (short)f2bf(bf2f((ushort_t)qf0[e]) * QSC);
    qf1[e] = (short)f2bf(bf2f((ushort_t)qf1[e]) * QSC);
  }
  float av = __expf(-(gq_raw[b * S_ + ic] + bgate[0]));
  float fdi = (i < S_) ? (float)i : -1e5f;

  int jlo = i0 - WIN_; if (jlo < 0) jlo = 0;
  int jt_lo = jlo >> 6;
  int jhi = i0 + 63 + WIN_; if (jhi > S_ - 1) jhi = S_ - 1;
  int jt_hi = jhi >> 6;
  int L = jt_hi - jt_lo + 1;                        // 17..33
  int n0 = (L + 2) / 3, n1 = (L + 1) / 3;
  int myLo = jt_lo + ((third == 0) ? 0 : (third == 1) ? n0 : n0 + n1);
  int cnt = (third == 0) ? n0 : (third == 1) ? n1 : L - n0 - n1;
  int myHi = myLo + cnt - 1;
  int jbase = myLo << 6;
  int nwin = cnt << 6;                              // <= 704

  for (int tt = tid; tt < nwin; tt += 256) {
    int j = jbase + tt; int jc = (j < S_) ? j : S_ - 1;
    gbs[tt] = __expf(-gk_raw[b * S_ + jc]);
  }

  // K staging map (64x64, 2 int4 per thread)
  int srow = tid >> 2, scol = (tid & 3) * 16;
  const ushort_t* kb_base = kb + (size_t)b * S_ * E_ + h * 64 + scol;
  // direct V row pointers: row d = nt*16+l15 fixed for this thread
  const ushort_t* vrow[4];
#pragma unroll
  for (int nt = 0; nt < 4; ++nt)
    vrow[nt] = vT + ((size_t)(b * H_ + h) * 64 + nt * 16 + l15) * SP_ + quad * 8;

  int4 ka0, ka1;
  {
    int jc0 = jbase + srow; if (jc0 > S_ - 1) jc0 = S_ - 1;
    const int4* kp = (const int4*)(kb_base + (size_t)jc0 * E_);
    ka0 = kp[0]; ka1 = kp[1];
  }

  const f32x4 fz = {0.f, 0.f, 0.f, 0.f};
  f32x4 Ov[4] = {fz, fz, fz, fz};
  float l_run = 0.f;

  for (int jt = myLo; jt <= myHi; ++jt) {
    int j0 = jt << 6;
    __syncthreads();
    int jn = (jt < myHi) ? ((jt + 1) << 6) : j0;
    int jcn = jn + srow; if (jcn > S_ - 1) jcn = S_ - 1;
    const int4* kp = (const int4*)(kb_base + (size_t)jcn * E_);
    int4 nk0 = kp[0], nk1 = kp[1];
    *(int4*)&Ks[srow][scol] = ka0; *(int4*)&Ks[srow][scol + 8] = ka1;
    __syncthreads();

    // issue V loads early (independent of LDS)
    bf16x8 vf0[4], vf1[4];
#pragma unroll
    for (int nt = 0; nt < 4; ++nt) {
      vf0[nt] = *(const bf16x8*)(vrow[nt] + j0);
      vf1[nt] = *(const bf16x8*)(vrow[nt] + j0 + 32);
    }

    // S^T = K . Q^T : lane holds one q-row (i=l15), 16 j's
    f32x4 st[4];
#pragma unroll
    for (int nt = 0; nt < 4; ++nt) {
      bf16x8 kf0 = *(const bf16x8*)&Ks[nt * 16 + l15][quad * 8];
      bf16x8 kf1 = *(const bf16x8*)&Ks[nt * 16 + l15][32 + quad * 8];
      f32x4 s = MFMA16(kf0, qf0, fz);
      st[nt] = MFMA16(kf1, qf1, s);
    }

    bool full = ((j0 + 63 - i0) <= WIN_) && ((i0 + 63 - j0) <= WIN_)
                && (j0 + 63 < S_) && (i0 + 63 < S_);
    float ps = 0.f;
    float fq = fdi - (float)(j0 + quad * 4);
    if (full) {
#pragma unroll
      for (int nt = 0; nt < 4; ++nt) {
        f32x4 g4 = *(const f32x4*)&gbs[(j0 - jbase) + nt * 16 + quad * 4];
#pragma unroll
        for (int r = 0; r < 4; ++r) {
          float f = fq - (float)(nt * 16 + r);
          float gate = __builtin_amdgcn_rcpf(fmaf(av, g4[r], 1.f));
          float p = __builtin_amdgcn_exp2f(fmaf(f * f, coef2, st[nt][r]) * gate);
          st[nt][r] = p; ps += p;
        }
      }
    } else {
#pragma unroll
      for (int nt = 0; nt < 4; ++nt) {
        f32x4 g4 = *(const f32x4*)&gbs[(j0 - jbase) + nt * 16 + quad * 4];
#pragma unroll
        for (int r = 0; r < 4; ++r) {
          int j = j0 + nt * 16 + quad * 4 + r;
          float fj = (j < S_) ? (float)j : 1e5f;
          float f = fdi - fj;
          float gate = __builtin_amdgcn_rcpf(fmaf(av, g4[r], 1.f));
          float t = fmaf(f * f, coef2, st[nt][r]) * gate;
          t = (__builtin_fabsf(f) <= 1024.f) ? t : -1e30f;
          float p = __builtin_amdgcn_exp2f(t);
          st[nt][r] = p; ps += p;
        }
      }
    }
    ps += __shfl_xor(ps, 16);
    ps += __shfl_xor(ps, 32);
    l_run += ps;

#pragma unroll
    for (int nt = 0; nt < 4; ++nt) {
      uint2 pk;
      pk.x = (unsigned int)f2bf(st[nt][0]) | ((unsigned int)f2bf(st[nt][1]) << 16);
      pk.y = (unsigned int)f2bf(st[nt][2]) | ((unsigned int)f2bf(st[nt][3]) << 16);
      *(uint2*)&Ps[w][l15][nt * 16 + quad * 4] = pk;
    }
    bf16x8 p0 = *(const bf16x8*)&Ps[w][l15][quad * 8];
    bf16x8 p1 = *(const bf16x8*)&Ps[w][l15][32 + quad * 8];
#pragma unroll
    for (int nt = 0; nt < 4; ++nt) {
      Ov[nt] = MFMA16(p0, vf0[nt], Ov[nt]);
      Ov[nt] = MFMA16(p1, vf1[nt], Ov[nt]);
    }
    ka0 = nk0; ka1 = nk1;
  }

  // store unnormalized partials (fp32)
  if (lane < 16) {
    int irow = i0 + w * 16 + lane;
    if (irow < S_)
      Lpart[(size_t)third * BHS_ + (size_t)(b * H_ + h) * S_ + irow] = l_run;
  }
#pragma unroll
  for (int r = 0; r < 4; ++r) {
    int irow = i0 + w * 16 + quad * 4 + r;
    if (irow < S_) {
      size_t base = ((size_t)third * BHS_ + (size_t)(b * H_ + h) * S_ + irow) * 64;
#pragma unroll
      for (int nt = 0; nt < 4; ++nt)
        Opart[base + nt * 16 + l15] = Ov[nt][r];
    }
  }
}

// ---------------------------------------------------------------------------
// Combine thirds: o = (O1+O2+O3)/(l1+l2+l3); emit hi/lo bf16, row-major.
// ---------------------------------------------------------------------------
__global__ __launch_bounds__(256) void combine_kernel(
    const float* __restrict__ Opart, const float* __restrict__ Lpart,
    ushort_t* __restrict__ ahi, ushort_t* __restrict__ alo)
{
  int tid = threadIdx.x;
  int gi = blockIdx.x * 16 + (tid >> 4);            // [0, 32784)
  int d4 = tid & 15;
  int b = gi / (H_ * S_);
  int rem = gi - b * (H_ * S_);
  int h = rem / S_;
  int i = rem - h * S_;
  size_t p0 = (size_t)(b * H_ + h) * S_ + i;
  float l = Lpart[p0] + Lpart[p0 + (size_t)BHS_] + Lpart[p0 + 2 * (size_t)BHS_];
  float inv = 1.f / l;
  const float* op = Opart + p0 * 64 + d4 * 4;
  float4 o1 = *(const float4*)op;
  float4 o2 = *(const float4*)(op + (size_t)BHS_ * 64);
  float4 o3 = *(const float4*)(op + 2 * (size_t)BHS_ * 64);
  float o[4] = {(o1.x + o2.x + o3.x) * inv, (o1.y + o2.y + o3.y) * inv,
                (o1.z + o2.z + o3.z) * inv, (o1.w + o2.w + o3.w) * inv};
  ushort4 hi, lo;
  hi.x = f2bf(o[0]); lo.x = f2bf(o[0] - bf2f(hi.x));
  hi.y = f2bf(o[1]); lo.y = f2bf(o[1] - bf2f(hi.y));
  hi.z = f2bf(o[2]); lo.z = f2bf(o[2] - bf2f(hi.z));
  hi.w = f2bf(o[3]); lo.w = f2bf(o[3] - bf2f(hi.w));
  size_t oidx = ((size_t)b * S_ + i) * E_ + h * 64 + d4 * 4;
  *(ushort4*)&ahi[oidx] = hi;
  *(ushort4*)&alo[oidx] = lo;
}

// ---------------------------------------------------------------------------
// Output projection, 64x128 tile, 2x2 waves (32x64 each), 2-term split:
// C = (Ahi + Alo) @ Whi + bias (fp32 out). Grid (65,4), reg-prefetch.
// ---------------------------------------------------------------------------
__global__ __launch_bounds__(256) void gemm_out_kernel(
    const ushort_t* __restrict__ Ahi, const ushort_t* __restrict__ Alo,
    const ushort_t* __restrict__ Whi, const float* __restrict__ bias,
    float* __restrict__ C)
{
  __shared__ __align__(16) ushort_t AsH[64][40];
  __shared__ __align__(16) ushort_t AsL[64][40];
  __shared__ __align__(16) ushort_t BsW[128][40];
  int tid = threadIdx.x;
  int lane = tid & 63, w = tid >> 6;
  int l15 = lane & 15, quad = lane >> 4;
  int wm = (w & 1) * 32, wn = (w >> 1) * 64;
  int bm = blockIdx.x * 64, bn = blockIdx.y * 128;

  int sr = tid >> 2, sc = (tid & 3) * 8;
  int am = bm + sr; if (am >= MROWS) am = MROWS - 1;
  const ushort_t* ahp = Ahi + (size_t)am * E_ + sc;
  const ushort_t* alp = Alo + (size_t)am * E_ + sc;
  int br = tid >> 1, bc = (tid & 1) * 16;
  const ushort_t* bp = Whi + (size_t)(bn + br) * E_ + bc;

  const f32x4 fz = {0.f, 0.f, 0.f, 0.f};
  f32x4 acc[2][4];
#pragma unroll
  for (int mt = 0; mt < 2; ++mt)
#pragma unroll
    for (int nt = 0; nt < 4; ++nt) acc[mt][nt] = fz;

  int4 ph = *(const int4*)ahp, pl = *(const int4*)alp;
  int4 pb0 = *(const int4*)bp, pb1 = *(const int4*)(bp + 8);

  for (int k0 = 0; k0 < E_; k0 += 32) {
    __syncthreads();
    int kn = (k0 + 32 < E_) ? (k0 + 32) : k0;
    int4 nh = *(const int4*)(ahp + kn);
    int4 nl = *(const int4*)(alp + kn);
    int4 nb0 = *(const int4*)(bp + kn), nb1 = *(const int4*)(bp + kn + 8);
    *(int4*)&AsH[sr][sc] = ph;
    *(int4*)&AsL[sr][sc] = pl;
    *(int4*)&BsW[br][bc] = pb0; *(int4*)&BsW[br][bc + 8] = pb1;
    __syncthreads();
    bf16x8 ah[2], al[2], bw[4];
#pragma unroll
    for (int mt = 0; mt < 2; ++mt) {
      ah[mt] = *(const bf16x8*)&AsH[wm + mt * 16 + l15][quad * 8];
      al[mt] = *(const bf16x8*)&AsL[wm + mt * 16 + l15][quad * 8];
    }
#pragma unroll
    for (int nt = 0; nt < 4; ++nt) bw[nt] = *(const bf16x8*)&BsW[wn + nt * 16 + l15][quad * 8];
#pragma unroll
    for (int mt = 0; mt < 2; ++mt)
#pragma unroll
      for (int nt = 0; nt < 4; ++nt) {
        acc[mt][nt] = MFMA16(ah[mt], bw[nt], acc[mt][nt]);
        acc[mt][nt] = MFMA16(al[mt], bw[nt], acc[mt][nt]);
      }
    ph = nh; pl = nl; pb0 = nb0; pb1 = nb1;
  }
#pragma unroll
  for (int nt = 0; nt < 4; ++nt) {
    float bb = bias[bn + wn + nt * 16 + l15];
#pragma unroll
    for (int mt = 0; mt < 2; ++mt)
#pragma unroll
      for (int r = 0; r < 4; ++r) {
        int m = bm + wm + mt * 16 + quad * 4 + r;
        if (m < MROWS)
          C[(size_t)m * E_ + bn + wn + nt * 16 + l15] = acc[mt][nt][r] + bb;
      }
  }
}

// ---------------------------------------------------------------------------
extern "C" void kernel_launch(void* const* d_in, const int* in_sizes, int n_in,
                              void* d_out, int out_size, void* d_ws, size_t ws_size,
                              hipStream_t stream) {
  const float* x  = (const float*)d_in[0];
  const float* Wq = (const float*)d_in[1];
  const float* bq = (const float*)d_in[2];
  const float* Wk = (const float*)d_in[3];
  const float* bk = (const float*)d_in[4];
  const float* Wv = (const float*)d_in[5];
  const float* bv = (const float*)d_in[6];
  const float* Wo = (const float*)d_in[7];
  const float* bo = (const float*)d_in[8];
  const float* wg = (const float*)d_in[9];
  const float* bg = (const float*)d_in[10];

  char* p = (char*)d_ws;
  ushort_t* Wt_all = (ushort_t*)p; p += (size_t)3 * E_ * E_ * 2;         // 1.57 MB
  ushort_t* WoHi   = (ushort_t*)p; p += (size_t)E_ * E_ * 2;             // 0.52 MB
  ushort_t* qkb    = (ushort_t*)p; p += (size_t)2 * MROWS * E_ * 2;      // 8.39 MB
  ushort_t* vT     = (ushort_t*)p; p += (size_t)B_ * H_ * 64 * SP_ * 2;  // 4.46 MB
  float*    gacc   = (float*)p;    p += (size_t)2 * GBUFN * 4;           // 33 KB
  float*    Opart  = (float*)p;    p += (size_t)3 * BHS_ * 64 * 4;       // 25.2 MB
  float*    Lpart  = (float*)p;    p += (size_t)3 * BHS_ * 4;            // 0.39 MB
  // aHi/aLo alias qkb: q/k are dead once attn completes (stream-ordered).
  ushort_t* aHi    = qkb;
  ushort_t* aLo    = qkb + (size_t)MROWS * E_;                           // ~40.6 MB

  hipLaunchKernelGGL(convert_w_kernel, dim3(16, 16, 4), dim3(256), 0, stream,
                     Wq, Wk, Wv, Wo, Wt_all, WoHi, gacc);
  hipLaunchKernelGGL(gemm_qkv_kernel, dim3(66, 4, 3), dim3(256), 0, stream,
                     x, Wt_all, bq, bk, bv, wg, qkb, vT, gacc);
  hipLaunchKernelGGL(attn_kernel, dim3(33 * 48), dim3(256), 0, stream,
                     qkb, qkb + (size_t)MROWS * E_, vT, gacc, gacc + GBUFN, bg,
                     Opart, Lpart);
  hipLaunchKernelGGL(combine_kernel, dim3(2049), dim3(256), 0, stream,
                     Opart, Lpart, aHi, aLo);
  hipLaunchKernelGGL(gemm_out_kernel, dim3(65, 4), dim3(256), 0, stream,
                     aHi, aLo, WoHi, bo, (float*)d_out);
}

// Round 10
// 188.951 us; speedup vs baseline: 1.3126x; 1.3126x over previous
//
#include <hip/hip_runtime.h>
#include <cstdint>
#include <cstddef>

#define B_ 2
#define S_ 2049
#define E_ 512
#define H_ 8
#define WIN_ 1024
#define MROWS (B_*S_)     // 4098
#define SP_ 2176          // padded seq for vT cols
#define GBUFN 4104
#define BHS_ (B_*H_*S_)   // 32784

typedef unsigned short ushort_t;
typedef __attribute__((ext_vector_type(8))) short bf16x8;   // 8 bf16 (4 VGPRs)
typedef __attribute__((ext_vector_type(4))) float f32x4;

#define MFMA16(a,b,c) __builtin_amdgcn_mfma_f32_16x16x32_bf16(a,b,c,0,0,0)

__device__ __forceinline__ ushort_t f2bf(float f) {          // RNE fp32->bf16
  unsigned int u = __float_as_uint(f);
  u += 0x7fffu + ((u >> 16) & 1u);
  return (ushort_t)(u >> 16);
}
__device__ __forceinline__ float bf2f(ushort_t h) {
  return __uint_as_float(((unsigned int)h) << 16);
}

// ---------------------------------------------------------------------------
// W [k][n] fp32 -> Wt [n][k] bf16 (z<3: Wq/Wk/Wv; z==3: Wo -> WoHi).
// z==3 blocks also zero the gate accumulators (replaces memset launch).
// ---------------------------------------------------------------------------
__global__ __launch_bounds__(256) void convert_w_kernel(
    const float* __restrict__ W0, const float* __restrict__ W1,
    const float* __restrict__ W2, const float* __restrict__ W3,
    ushort_t* __restrict__ Wt_all, ushort_t* __restrict__ WoHi,
    float* __restrict__ gacc)
{
  __shared__ float tile[32][33];
  int z = blockIdx.z;
  if (z == 3) {
    int gz = (blockIdx.x * 16 + blockIdx.y) * 256 + threadIdx.x;
    if (gz < 2 * GBUFN) gacc[gz] = 0.f;
  }
  const float* W = (z == 0) ? W0 : (z == 1) ? W1 : (z == 2) ? W2 : W3;
  int k0 = blockIdx.x * 32, n0 = blockIdx.y * 32;
  int r = threadIdx.x >> 5, c = threadIdx.x & 31;
#pragma unroll
  for (int i = 0; i < 4; ++i) {
    int rr = r + i * 8;
    tile[rr][c] = W[(size_t)(k0 + rr) * E_ + n0 + c];
  }
  __syncthreads();
#pragma unroll
  for (int i = 0; i < 4; ++i) {
    int rr = r + i * 8;
    float v = tile[c][rr];                       // = W[k0+c][n0+rr]
    size_t dst = (size_t)(n0 + rr) * E_ + k0 + c;
    if (z < 3) Wt_all[(size_t)z * E_ * E_ + dst] = f2bf(v);
    else       WoHi[dst] = f2bf(v);
  }
}

// ---------------------------------------------------------------------------
// QKV projection, 64x128 tile, 2x2 waves (32x64 each), BK=32, reg-prefetch
// (R8 version — BK=64 spilled to scratch, 186MB HBM writes, 3x regression).
// Per-b m-tiling (grid.x=66). z<2: row-major bf16 + fused gate partial dots.
// z==2: LDS-transpose -> coalesced vT[b][h][d][i].
// ---------------------------------------------------------------------------
__global__ __launch_bounds__(256) void gemm_qkv_kernel(
    const float* __restrict__ x, const ushort_t* __restrict__ Wt_all,
    const float* __restrict__ bq, const float* __restrict__ bk,
    const float* __restrict__ bv, const float* __restrict__ wg,
    ushort_t* __restrict__ qkb, ushort_t* __restrict__ vT,
    float* __restrict__ gacc)
{
  __shared__ __align__(16) ushort_t As[64][40];
  __shared__ __align__(16) ushort_t Bs[128][40];
  int tid = threadIdx.x;
  int lane = tid & 63, w = tid >> 6;
  int l15 = lane & 15, quad = lane >> 4;
  int wm = (w & 1) * 32, wn = (w >> 1) * 64;
  int z = blockIdx.z;
  const ushort_t* Wt = Wt_all + (size_t)z * E_ * E_;
  const float* bias = (z == 0) ? bq : (z == 1) ? bk : bv;
  int bt = blockIdx.x;               // 0..65; 33 i-tiles per batch
  int bg2 = bt / 33;                 // batch b
  int bm = (bt - bg2 * 33) * 64;     // i-tile base within batch
  int bn = blockIdx.y * 128;
  size_t rowbase = (size_t)bg2 * S_;

  int ar = tid >> 2, acq = (tid & 3) * 8;
  int ai = bm + ar; if (ai >= S_) ai = S_ - 1;
  const float* ap = x + (rowbase + ai) * E_ + acq;
  int br = tid >> 1, bcq = (tid & 1) * 16;
  const ushort_t* bp = Wt + (size_t)(bn + br) * E_ + bcq;

  const f32x4 fz = {0.f, 0.f, 0.f, 0.f};
  f32x4 acc[2][4];
#pragma unroll
  for (int mt = 0; mt < 2; ++mt)
#pragma unroll
    for (int nt = 0; nt < 4; ++nt) acc[mt][nt] = fz;

  float4 pa0 = *(const float4*)ap, pa1 = *(const float4*)(ap + 4);
  int4  pb0 = *(const int4*)bp,   pb1 = *(const int4*)(bp + 8);

  for (int k0 = 0; k0 < E_; k0 += 32) {
    __syncthreads();
    int kn = (k0 + 32 < E_) ? (k0 + 32) : k0;
    float4 na0 = *(const float4*)(ap + kn), na1 = *(const float4*)(ap + kn + 4);
    int4  nb0 = *(const int4*)(bp + kn),   nb1 = *(const int4*)(bp + kn + 8);
    union { int4 v; ushort_t u[8]; } cv;
    cv.u[0] = f2bf(pa0.x); cv.u[1] = f2bf(pa0.y); cv.u[2] = f2bf(pa0.z); cv.u[3] = f2bf(pa0.w);
    cv.u[4] = f2bf(pa1.x); cv.u[5] = f2bf(pa1.y); cv.u[6] = f2bf(pa1.z); cv.u[7] = f2bf(pa1.w);
    *(int4*)&As[ar][acq] = cv.v;
    *(int4*)&Bs[br][bcq] = pb0; *(int4*)&Bs[br][bcq + 8] = pb1;
    __syncthreads();
    bf16x8 a[2], bfr[4];
#pragma unroll
    for (int mt = 0; mt < 2; ++mt) a[mt] = *(const bf16x8*)&As[wm + mt * 16 + l15][quad * 8];
#pragma unroll
    for (int nt = 0; nt < 4; ++nt) bfr[nt] = *(const bf16x8*)&Bs[wn + nt * 16 + l15][quad * 8];
#pragma unroll
    for (int mt = 0; mt < 2; ++mt)
#pragma unroll
      for (int nt = 0; nt < 4; ++nt)
        acc[mt][nt] = MFMA16(a[mt], bfr[nt], acc[mt][nt]);
    pa0 = na0; pa1 = na1; pb0 = nb0; pb1 = nb1;
  }

  float bb[4];
#pragma unroll
  for (int nt = 0; nt < 4; ++nt) bb[nt] = bias[bn + wn + nt * 16 + l15];

  if (z < 2) {
    ushort_t* C = qkb + (size_t)z * MROWS * E_;
#pragma unroll
    for (int mt = 0; mt < 2; ++mt)
#pragma unroll
      for (int nt = 0; nt < 4; ++nt)
#pragma unroll
        for (int r = 0; r < 4; ++r) {
          int i = bm + wm + mt * 16 + quad * 4 + r;
          if (i < S_)
            C[(rowbase + i) * E_ + bn + wn + nt * 16 + l15] = f2bf(acc[mt][nt][r] + bb[nt]);
        }
    // fused gate partial dots
    const float* wgp = wg + (size_t)z * E_;
    float wv[4];
#pragma unroll
    for (int nt = 0; nt < 4; ++nt) wv[nt] = wgp[bn + wn + nt * 16 + l15];
    float* gp = gacc + (size_t)z * GBUFN;
#pragma unroll
    for (int mt = 0; mt < 2; ++mt)
#pragma unroll
      for (int r = 0; r < 4; ++r) {
        float s = 0.f;
#pragma unroll
        for (int nt = 0; nt < 4; ++nt) s = fmaf(acc[mt][nt][r] + bb[nt], wv[nt], s);
        s += __shfl_xor(s, 1, 16); s += __shfl_xor(s, 2, 16);
        s += __shfl_xor(s, 4, 16); s += __shfl_xor(s, 8, 16);
        int i = bm + wm + mt * 16 + quad * 4 + r;
        if (l15 == 0 && i < S_) atomicAdd(&gp[rowbase + i], s);
      }
  } else {
    // v: LDS transpose (2-way conflicts = free) then coalesced aligned int4
    ushort_t* lt = &Bs[0][0];                    // 64d x 72i tile
    int ti = tid >> 2, tc = (tid & 3) * 16;
#pragma unroll
    for (int hh = 0; hh < 2; ++hh) {
      __syncthreads();
      if ((w >> 1) == hh) {
#pragma unroll
        for (int mt = 0; mt < 2; ++mt)
#pragma unroll
          for (int nt = 0; nt < 4; ++nt) {
            int d = nt * 16 + l15;
#pragma unroll
            for (int r = 0; r < 4; ++r) {
              int il = wm + mt * 16 + quad * 4 + r;
              lt[d * 72 + il] = f2bf(acc[mt][nt][r] + bb[nt]);
            }
          }
      }
      __syncthreads();
      int hg = (bn >> 6) + hh;
      union { int4 q[2]; ushort_t u[16]; } tv;
      tv.q[0] = *(const int4*)&lt[ti * 72 + tc];
      tv.q[1] = *(const int4*)&lt[ti * 72 + tc + 8];
      size_t vrow = ((size_t)(bg2 * H_ + hg) * 64 + ti) * SP_;
#pragma unroll
      for (int c8 = 0; c8 < 2; ++c8) {
        int i2 = bm + tc + c8 * 8;
        if (i2 + 7 < S_) {
          *(int4*)&vT[vrow + i2] = tv.q[c8];
        } else {
#pragma unroll
          for (int e = 0; e < 8; ++e)
            if (i2 + e < S_) vT[vrow + i2 + e] = tv.u[c8 * 8 + e];
        }
      }
    }
  }
}

// ---------------------------------------------------------------------------
// MFMA flash attention, S^T form, fixed-reference softmax, thirds split.
// V B-fragments read DIRECT from global vT (L2-resident; layout matches the
// MFMA B-operand exactly) -> no Vt LDS buffer: 21.3KB LDS, 7 blocks/CU.
// Q pre-scaled by 0.125*log2e; p = exp2(...) (raw v_exp, no mul).
// ---------------------------------------------------------------------------
__global__ __launch_bounds__(256) void attn_kernel(
    const ushort_t* __restrict__ qb, const ushort_t* __restrict__ kb,
    const ushort_t* __restrict__ vT, const float* __restrict__ gq_raw,
    const float* __restrict__ gk_raw, const float* __restrict__ bgate,
    float* __restrict__ Opart, float* __restrict__ Lpart)
{
  __shared__ __align__(16) ushort_t Ks[64][72];    // [j][d]
  __shared__ __align__(16) ushort_t Ps[4][16][72]; // per-wave P [i][j]
  __shared__ float gbs[704];

  int tid = threadIdx.x;
  int lane = tid & 63, w = tid >> 6;
  int l15 = lane & 15, quad = lane >> 4;

  // middle-out q-tile order; 48 blocks (16 bh x 3 thirds) per qt
  int sub = blockIdx.x % 48;
  int qidx = blockIdx.x / 48;
  int off = (qidx + 1) >> 1;
  int qt = 16 + ((qidx & 1) ? -off : off);          // 0..32
  int bh = sub & 15, third = sub >> 4;
  int h = bh & 7, b = bh >> 3;
  int i0 = qt * 64;
  const float LOG2E = 1.44269504f;
  const float coef2 = (-0.5f / (512.f * 512.f)) * LOG2E;
  const float QSC = 0.125f * LOG2E;

  // per-thread q-row
  int i = i0 + w * 16 + l15;
  int ic = (i < S_) ? i : S_ - 1;
  bf16x8 qf0 = *(const bf16x8*)&qb[((size_t)(b * S_ + ic)) * E_ + h * 64 + quad * 8];
  bf16x8 qf1 = *(const bf16x8*)&qb[((size_t)(b * S_ + ic)) * E_ + h * 64 + 32 + quad * 8];
#pragma unroll
  for (int e = 0; e < 8; ++e) {                     // fold D^-0.5 * log2e into Q
    qf0[e] = (short)f2bf(bf2f((ushort_t)qf0[e]) * QSC);
    qf1[e] = (short)f2bf(bf2f((ushort_t)qf1[e]) * QSC);
  }
  float av = __expf(-(gq_raw[b * S_ + ic] + bgate[0]));
  float fdi = (i < S_) ? (float)i : -1e5f;

  int jlo = i0 - WIN_; if (jlo < 0) jlo = 0;
  int jt_lo = jlo >> 6;
  int jhi = i0 + 63 + WIN_; if (jhi > S_ - 1) jhi = S_ - 1;
  int jt_hi = jhi >> 6;
  int L = jt_hi - jt_lo + 1;                        // 17..33
  int n0 = (L + 2) / 3, n1 = (L + 1) / 3;
  int myLo = jt_lo + ((third == 0) ? 0 : (third == 1) ? n0 : n0 + n1);
  int cnt = (third == 0) ? n0 : (third == 1) ? n1 : L - n0 - n1;
  int myHi = myLo + cnt - 1;
  int jbase = myLo << 6;
  int nwin = cnt << 6;                              // <= 704

  for (int tt = tid; tt < nwin; tt += 256) {
    int j = jbase + tt; int jc = (j < S_) ? j : S_ - 1;
    gbs[tt] = __expf(-gk_raw[b * S_ + jc]);
  }

  // K staging map (64x64, 2 int4 per thread)
  int srow = tid >> 2, scol = (tid & 3) * 16;
  const ushort_t* kb_base = kb + (size_t)b * S_ * E_ + h * 64 + scol;
  // direct V row pointers: row d = nt*16+l15 fixed for this thread
  const ushort_t* vrow[4];
#pragma unroll
  for (int nt = 0; nt < 4; ++nt)
    vrow[nt] = vT + ((size_t)(b * H_ + h) * 64 + nt * 16 + l15) * SP_ + quad * 8;

  int4 ka0, ka1;
  {
    int jc0 = jbase + srow; if (jc0 > S_ - 1) jc0 = S_ - 1;
    const int4* kp = (const int4*)(kb_base + (size_t)jc0 * E_);
    ka0 = kp[0]; ka1 = kp[1];
  }

  const f32x4 fz = {0.f, 0.f, 0.f, 0.f};
  f32x4 Ov[4] = {fz, fz, fz, fz};
  float l_run = 0.f;

  for (int jt = myLo; jt <= myHi; ++jt) {
    int j0 = jt << 6;
    __syncthreads();
    int jn = (jt < myHi) ? ((jt + 1) << 6) : j0;
    int jcn = jn + srow; if (jcn > S_ - 1) jcn = S_ - 1;
    const int4* kp = (const int4*)(kb_base + (size_t)jcn * E_);
    int4 nk0 = kp[0], nk1 = kp[1];
    *(int4*)&Ks[srow][scol] = ka0; *(int4*)&Ks[srow][scol + 8] = ka1;
    __syncthreads();

    // issue V loads early (independent of LDS)
    bf16x8 vf0[4], vf1[4];
#pragma unroll
    for (int nt = 0; nt < 4; ++nt) {
      vf0[nt] = *(const bf16x8*)(vrow[nt] + j0);
      vf1[nt] = *(const bf16x8*)(vrow[nt] + j0 + 32);
    }

    // S^T = K . Q^T : lane holds one q-row (i=l15), 16 j's
    f32x4 st[4];
#pragma unroll
    for (int nt = 0; nt < 4; ++nt) {
      bf16x8 kf0 = *(const bf16x8*)&Ks[nt * 16 + l15][quad * 8];
      bf16x8 kf1 = *(const bf16x8*)&Ks[nt * 16 + l15][32 + quad * 8];
      f32x4 s = MFMA16(kf0, qf0, fz);
      st[nt] = MFMA16(kf1, qf1, s);
    }

    bool full = ((j0 + 63 - i0) <= WIN_) && ((i0 + 63 - j0) <= WIN_)
                && (j0 + 63 < S_) && (i0 + 63 < S_);
    float ps = 0.f;
    float fq = fdi - (float)(j0 + quad * 4);
    if (full) {
#pragma unroll
      for (int nt = 0; nt < 4; ++nt) {
        f32x4 g4 = *(const f32x4*)&gbs[(j0 - jbase) + nt * 16 + quad * 4];
#pragma unroll
        for (int r = 0; r < 4; ++r) {
          float f = fq - (float)(nt * 16 + r);
          float gate = __builtin_amdgcn_rcpf(fmaf(av, g4[r], 1.f));
          float p = __builtin_amdgcn_exp2f(fmaf(f * f, coef2, st[nt][r]) * gate);
          st[nt][r] = p; ps += p;
        }
      }
    } else {
#pragma unroll
      for (int nt = 0; nt < 4; ++nt) {
        f32x4 g4 = *(const f32x4*)&gbs[(j0 - jbase) + nt * 16 + quad * 4];
#pragma unroll
        for (int r = 0; r < 4; ++r) {
          int j = j0 + nt * 16 + quad * 4 + r;
          float fj = (j < S_) ? (float)j : 1e5f;
          float f = fdi - fj;
          float gate = __builtin_amdgcn_rcpf(fmaf(av, g4[r], 1.f));
          float t = fmaf(f * f, coef2, st[nt][r]) * gate;
          t = (__builtin_fabsf(f) <= 1024.f) ? t : -1e30f;
          float p = __builtin_amdgcn_exp2f(t);
          st[nt][r] = p; ps += p;
        }
      }
    }
    ps += __shfl_xor(ps, 16);
    ps += __shfl_xor(ps, 32);
    l_run += ps;

#pragma unroll
    for (int nt = 0; nt < 4; ++nt) {
      uint2 pk;
      pk.x = (unsigned int)f2bf(st[nt][0]) | ((unsigned int)f2bf(st[nt][1]) << 16);
      pk.y = (unsigned int)f2bf(st[nt][2]) | ((unsigned int)f2bf(st[nt][3]) << 16);
      *(uint2*)&Ps[w][l15][nt * 16 + quad * 4] = pk;
    }
    bf16x8 p0 = *(const bf16x8*)&Ps[w][l15][quad * 8];
    bf16x8 p1 = *(const bf16x8*)&Ps[w][l15][32 + quad * 8];
#pragma unroll
    for (int nt = 0; nt < 4; ++nt) {
      Ov[nt] = MFMA16(p0, vf0[nt], Ov[nt]);
      Ov[nt] = MFMA16(p1, vf1[nt], Ov[nt]);
    }
    ka0 = nk0; ka1 = nk1;
  }

  // store unnormalized partials (fp32)
  if (lane < 16) {
    int irow = i0 + w * 16 + lane;
    if (irow < S_)
      Lpart[(size_t)third * BHS_ + (size_t)(b * H_ + h) * S_ + irow] = l_run;
  }
#pragma unroll
  for (int r = 0; r < 4; ++r) {
    int irow = i0 + w * 16 + quad * 4 + r;
    if (irow < S_) {
      size_t base = ((size_t)third * BHS_ + (size_t)(b * H_ + h) * S_ + irow) * 64;
#pragma unroll
      for (int nt = 0; nt < 4; ++nt)
        Opart[base + nt * 16 + l15] = Ov[nt][r];
    }
  }
}

// ---------------------------------------------------------------------------
// Combine thirds: o = (O1+O2+O3)/(l1+l2+l3); emit hi/lo bf16, row-major.
// ---------------------------------------------------------------------------
__global__ __launch_bounds__(256) void combine_kernel(
    const float* __restrict__ Opart, const float* __restrict__ Lpart,
    ushort_t* __restrict__ ahi, ushort_t* __restrict__ alo)
{
  int tid = threadIdx.x;
  int gi = blockIdx.x * 16 + (tid >> 4);            // [0, 32784)
  int d4 = tid & 15;
  int b = gi / (H_ * S_);
  int rem = gi - b * (H_ * S_);
  int h = rem / S_;
  int i = rem - h * S_;
  size_t p0 = (size_t)(b * H_ + h) * S_ + i;
  float l = Lpart[p0] + Lpart[p0 + (size_t)BHS_] + Lpart[p0 + 2 * (size_t)BHS_];
  float inv = 1.f / l;
  const float* op = Opart + p0 * 64 + d4 * 4;
  float4 o1 = *(const float4*)op;
  float4 o2 = *(const float4*)(op + (size_t)BHS_ * 64);
  float4 o3 = *(const float4*)(op + 2 * (size_t)BHS_ * 64);
  float o[4] = {(o1.x + o2.x + o3.x) * inv, (o1.y + o2.y + o3.y) * inv,
                (o1.z + o2.z + o3.z) * inv, (o1.w + o2.w + o3.w) * inv};
  ushort4 hi, lo;
  hi.x = f2bf(o[0]); lo.x = f2bf(o[0] - bf2f(hi.x));
  hi.y = f2bf(o[1]); lo.y = f2bf(o[1] - bf2f(hi.y));
  hi.z = f2bf(o[2]); lo.z = f2bf(o[2] - bf2f(hi.z));
  hi.w = f2bf(o[3]); lo.w = f2bf(o[3] - bf2f(hi.w));
  size_t oidx = ((size_t)b * S_ + i) * E_ + h * 64 + d4 * 4;
  *(ushort4*)&ahi[oidx] = hi;
  *(ushort4*)&alo[oidx] = lo;
}

// ---------------------------------------------------------------------------
// Output projection, 64x128 tile, 2x2 waves (32x64 each), 2-term split:
// C = (Ahi + Alo) @ Whi + bias (fp32 out). Grid (65,4), reg-prefetch.
// ---------------------------------------------------------------------------
__global__ __launch_bounds__(256) void gemm_out_kernel(
    const ushort_t* __restrict__ Ahi, const ushort_t* __restrict__ Alo,
    const ushort_t* __restrict__ Whi, const float* __restrict__ bias,
    float* __restrict__ C)
{
  __shared__ __align__(16) ushort_t AsH[64][40];
  __shared__ __align__(16) ushort_t AsL[64][40];
  __shared__ __align__(16) ushort_t BsW[128][40];
  int tid = threadIdx.x;
  int lane = tid & 63, w = tid >> 6;
  int l15 = lane & 15, quad = lane >> 4;
  int wm = (w & 1) * 32, wn = (w >> 1) * 64;
  int bm = blockIdx.x * 64, bn = blockIdx.y * 128;

  int sr = tid >> 2, sc = (tid & 3) * 8;
  int am = bm + sr; if (am >= MROWS) am = MROWS - 1;
  const ushort_t* ahp = Ahi + (size_t)am * E_ + sc;
  const ushort_t* alp = Alo + (size_t)am * E_ + sc;
  int br = tid >> 1, bc = (tid & 1) * 16;
  const ushort_t* bp = Whi + (size_t)(bn + br) * E_ + bc;

  const f32x4 fz = {0.f, 0.f, 0.f, 0.f};
  f32x4 acc[2][4];
#pragma unroll
  for (int mt = 0; mt < 2; ++mt)
#pragma unroll
    for (int nt = 0; nt < 4; ++nt) acc[mt][nt] = fz;

  int4 ph = *(const int4*)ahp, pl = *(const int4*)alp;
  int4 pb0 = *(const int4*)bp, pb1 = *(const int4*)(bp + 8);

  for (int k0 = 0; k0 < E_; k0 += 32) {
    __syncthreads();
    int kn = (k0 + 32 < E_) ? (k0 + 32) : k0;
    int4 nh = *(const int4*)(ahp + kn);
    int4 nl = *(const int4*)(alp + kn);
    int4 nb0 = *(const int4*)(bp + kn), nb1 = *(const int4*)(bp + kn + 8);
    *(int4*)&AsH[sr][sc] = ph;
    *(int4*)&AsL[sr][sc] = pl;
    *(int4*)&BsW[br][bc] = pb0; *(int4*)&BsW[br][bc + 8] = pb1;
    __syncthreads();
    bf16x8 ah[2], al[2], bw[4];
#pragma unroll
    for (int mt = 0; mt < 2; ++mt) {
      ah[mt] = *(const bf16x8*)&AsH[wm + mt * 16 + l15][quad * 8];
      al[mt] = *(const bf16x8*)&AsL[wm + mt * 16 + l15][quad * 8];
    }
#pragma unroll
    for (int nt = 0; nt < 4; ++nt) bw[nt] = *(const bf16x8*)&BsW[wn + nt * 16 + l15][quad * 8];
#pragma unroll
    for (int mt = 0; mt < 2; ++mt)
#pragma unroll
      for (int nt = 0; nt < 4; ++nt) {
        acc[mt][nt] = MFMA16(ah[mt], bw[nt], acc[mt][nt]);
        acc[mt][nt] = MFMA16(al[mt], bw[nt], acc[mt][nt]);
      }
    ph = nh; pl = nl; pb0 = nb0; pb1 = nb1;
  }
#pragma unroll
  for (int nt = 0; nt < 4; ++nt) {
    float bb = bias[bn + wn + nt * 16 + l15];
#pragma unroll
    for (int mt = 0; mt < 2; ++mt)
#pragma unroll
      for (int r = 0; r < 4; ++r) {
        int m = bm + wm + mt * 16 + quad * 4 + r;
        if (m < MROWS)
          C[(size_t)m * E_ + bn + wn + nt * 16 + l15] = acc[mt][nt][r] + bb;
      }
  }
}

// ---------------------------------------------------------------------------
extern "C" void kernel_launch(void* const* d_in, const int* in_sizes, int n_in,
                              void* d_out, int out_size, void* d_ws, size_t ws_size,
                              hipStream_t stream) {
  const float* x  = (const float*)d_in[0];
  const float* Wq = (const float*)d_in[1];
  const float* bq = (const float*)d_in[2];
  const float* Wk = (const float*)d_in[3];
  const float* bk = (const float*)d_in[4];
  const float* Wv = (const float*)d_in[5];
  const float* bv = (const float*)d_in[6];
  const float* Wo = (const float*)d_in[7];
  const float* bo = (const float*)d_in[8];
  const float* wg = (const float*)d_in[9];
  const float* bg = (const float*)d_in[10];

  char* p = (char*)d_ws;
  ushort_t* Wt_all = (ushort_t*)p; p += (size_t)3 * E_ * E_ * 2;         // 1.57 MB
  ushort_t* WoHi   = (ushort_t*)p; p += (size_t)E_ * E_ * 2;             // 0.52 MB
  ushort_t* qkb    = (ushort_t*)p; p += (size_t)2 * MROWS * E_ * 2;      // 8.39 MB
  ushort_t* vT     = (ushort_t*)p; p += (size_t)B_ * H_ * 64 * SP_ * 2;  // 4.46 MB
  float*    gacc   = (float*)p;    p += (size_t)2 * GBUFN * 4;           // 33 KB
  float*    Opart  = (float*)p;    p += (size_t)3 * BHS_ * 64 * 4;       // 25.2 MB
  float*    Lpart  = (float*)p;    p += (size_t)3 * BHS_ * 4;            // 0.39 MB
  // aHi/aLo alias qkb: q/k are dead once attn completes (stream-ordered).
  ushort_t* aHi    = qkb;
  ushort_t* aLo    = qkb + (size_t)MROWS * E_;                           // ~40.6 MB

  hipLaunchKernelGGL(convert_w_kernel, dim3(16, 16, 4), dim3(256), 0, stream,
                     Wq, Wk, Wv, Wo, Wt_all, WoHi, gacc);
  hipLaunchKernelGGL(gemm_qkv_kernel, dim3(66, 4, 3), dim3(256), 0, stream,
                     x, Wt_all, bq, bk, bv, wg, qkb, vT, gacc);
  hipLaunchKernelGGL(attn_kernel, dim3(33 * 48), dim3(256), 0, stream,
                     qkb, qkb + (size_t)MROWS * E_, vT, gacc, gacc + GBUFN, bg,
                     Opart, Lpart);
  hipLaunchKernelGGL(combine_kernel, dim3(2049), dim3(256), 0, stream,
                     Opart, Lpart, aHi, aLo);
  hipLaunchKernelGGL(gemm_out_kernel, dim3(65, 4), dim3(256), 0, stream,
                     aHi, aLo, WoHi, bo, (float*)d_out);
}

// Round 11
// 162.488 us; speedup vs baseline: 1.5264x; 1.1629x over previous
//
#include <hip/hip_runtime.h>
#include <cstdint>
#include <cstddef>

#define B_ 2
#define S_ 2049
#define E_ 512
#define H_ 8
#define WIN_ 1024
#define MROWS (B_*S_)     // 4098
#define SP_ 2176          // padded seq for vT cols
#define GBUFN 4104
#define BHS_ (B_*H_*S_)   // 32784

typedef unsigned short ushort_t;
typedef __attribute__((ext_vector_type(8))) short bf16x8;   // 8 bf16 (4 VGPRs)
typedef __attribute__((ext_vector_type(4))) float f32x4;

#define MFMA16(a,b,c) __builtin_amdgcn_mfma_f32_16x16x32_bf16(a,b,c,0,0,0)

__device__ __forceinline__ ushort_t f2bf(float f) {          // RNE fp32->bf16
  unsigned int u = __float_as_uint(f);
  u += 0x7fffu + ((u >> 16) & 1u);
  return (ushort_t)(u >> 16);
}
__device__ __forceinline__ float bf2f(ushort_t h) {
  return __uint_as_float(((unsigned int)h) << 16);
}

// ---------------------------------------------------------------------------
// One launch: blocks [0,2049) convert x fp32->bf16 (coalesced float4);
// blocks [2049,3073): W [k][n] -> Wt [n][k] bf16 (z<3) / WoHi (z==3),
// z==3 blocks also zero the gate accumulators.
// ---------------------------------------------------------------------------
__global__ __launch_bounds__(256) void convert_all_kernel(
    const float* __restrict__ x, const float* __restrict__ W0,
    const float* __restrict__ W1, const float* __restrict__ W2,
    const float* __restrict__ W3, ushort_t* __restrict__ xb,
    ushort_t* __restrict__ Wt_all, ushort_t* __restrict__ WoHi,
    float* __restrict__ gacc)
{
  __shared__ float tile[32][33];
  int bid = blockIdx.x;
  if (bid < 2049) {
    int idx = bid * 256 + threadIdx.x;               // exactly MROWS*E_/4
    float4 v = ((const float4*)x)[idx];
    ushort4 o;
    o.x = f2bf(v.x); o.y = f2bf(v.y); o.z = f2bf(v.z); o.w = f2bf(v.w);
    ((ushort4*)xb)[idx] = o;
    return;
  }
  int wid = bid - 2049;
  int z = wid >> 8, rem = wid & 255;
  if (z == 3) {
    int gz = rem * 256 + threadIdx.x;
    if (gz < 2 * GBUFN) gacc[gz] = 0.f;
  }
  const float* W = (z == 0) ? W0 : (z == 1) ? W1 : (z == 2) ? W2 : W3;
  int k0 = (rem >> 4) * 32, n0 = (rem & 15) * 32;
  int r = threadIdx.x >> 5, c = threadIdx.x & 31;
#pragma unroll
  for (int i = 0; i < 4; ++i) {
    int rr = r + i * 8;
    tile[rr][c] = W[(size_t)(k0 + rr) * E_ + n0 + c];
  }
  __syncthreads();
#pragma unroll
  for (int i = 0; i < 4; ++i) {
    int rr = r + i * 8;
    float v = tile[c][rr];                       // = W[k0+c][n0+rr]
    size_t dst = (size_t)(n0 + rr) * E_ + k0 + c;
    if (z < 3) Wt_all[(size_t)z * E_ * E_ + dst] = f2bf(v);
    else       WoHi[dst] = f2bf(v);
  }
}

// ---------------------------------------------------------------------------
// QKV projection, 64x128 tile, 2x2 waves (32x64 each), BK=32, reg-prefetch,
// bf16 xb input (halves A traffic vs fp32 x; no in-loop convert).
// Per-b m-tiling (grid.x=66). z<2: row-major bf16 + fused gate partial dots.
// z==2: LDS-transpose -> coalesced vT[b][h][d][i].
// ---------------------------------------------------------------------------
__global__ __launch_bounds__(256) void gemm_qkv_kernel(
    const ushort_t* __restrict__ xb, const ushort_t* __restrict__ Wt_all,
    const float* __restrict__ bq, const float* __restrict__ bk,
    const float* __restrict__ bv, const float* __restrict__ wg,
    ushort_t* __restrict__ qkb, ushort_t* __restrict__ vT,
    float* __restrict__ gacc)
{
  __shared__ __align__(16) ushort_t As[64][40];
  __shared__ __align__(16) ushort_t Bs[128][40];
  int tid = threadIdx.x;
  int lane = tid & 63, w = tid >> 6;
  int l15 = lane & 15, quad = lane >> 4;
  int wm = (w & 1) * 32, wn = (w >> 1) * 64;
  int z = blockIdx.z;
  const ushort_t* Wt = Wt_all + (size_t)z * E_ * E_;
  const float* bias = (z == 0) ? bq : (z == 1) ? bk : bv;
  int bt = blockIdx.x;               // 0..65; 33 i-tiles per batch
  int bg2 = bt / 33;                 // batch b
  int bm = (bt - bg2 * 33) * 64;     // i-tile base within batch
  int bn = blockIdx.y * 128;
  size_t rowbase = (size_t)bg2 * S_;

  int ar = tid >> 2, acq = (tid & 3) * 8;
  int ai = bm + ar; if (ai >= S_) ai = S_ - 1;
  const ushort_t* ap = xb + (rowbase + ai) * E_ + acq;
  int br = tid >> 1, bcq = (tid & 1) * 16;
  const ushort_t* bp = Wt + (size_t)(bn + br) * E_ + bcq;

  const f32x4 fz = {0.f, 0.f, 0.f, 0.f};
  f32x4 acc[2][4];
#pragma unroll
  for (int mt = 0; mt < 2; ++mt)
#pragma unroll
    for (int nt = 0; nt < 4; ++nt) acc[mt][nt] = fz;

  int4 pa = *(const int4*)ap;
  int4 pb0 = *(const int4*)bp, pb1 = *(const int4*)(bp + 8);

  for (int k0 = 0; k0 < E_; k0 += 32) {
    __syncthreads();
    int kn = (k0 + 32 < E_) ? (k0 + 32) : k0;
    int4 na = *(const int4*)(ap + kn);
    int4 nb0 = *(const int4*)(bp + kn), nb1 = *(const int4*)(bp + kn + 8);
    *(int4*)&As[ar][acq] = pa;
    *(int4*)&Bs[br][bcq] = pb0; *(int4*)&Bs[br][bcq + 8] = pb1;
    __syncthreads();
    bf16x8 a[2], bfr[4];
#pragma unroll
    for (int mt = 0; mt < 2; ++mt) a[mt] = *(const bf16x8*)&As[wm + mt * 16 + l15][quad * 8];
#pragma unroll
    for (int nt = 0; nt < 4; ++nt) bfr[nt] = *(const bf16x8*)&Bs[wn + nt * 16 + l15][quad * 8];
#pragma unroll
    for (int mt = 0; mt < 2; ++mt)
#pragma unroll
      for (int nt = 0; nt < 4; ++nt)
        acc[mt][nt] = MFMA16(a[mt], bfr[nt], acc[mt][nt]);
    pa = na; pb0 = nb0; pb1 = nb1;
  }

  float bb[4];
#pragma unroll
  for (int nt = 0; nt < 4; ++nt) bb[nt] = bias[bn + wn + nt * 16 + l15];

  if (z < 2) {
    ushort_t* C = qkb + (size_t)z * MROWS * E_;
#pragma unroll
    for (int mt = 0; mt < 2; ++mt)
#pragma unroll
      for (int nt = 0; nt < 4; ++nt)
#pragma unroll
        for (int r = 0; r < 4; ++r) {
          int i = bm + wm + mt * 16 + quad * 4 + r;
          if (i < S_)
            C[(rowbase + i) * E_ + bn + wn + nt * 16 + l15] = f2bf(acc[mt][nt][r] + bb[nt]);
        }
    // fused gate partial dots
    const float* wgp = wg + (size_t)z * E_;
    float wv[4];
#pragma unroll
    for (int nt = 0; nt < 4; ++nt) wv[nt] = wgp[bn + wn + nt * 16 + l15];
    float* gp = gacc + (size_t)z * GBUFN;
#pragma unroll
    for (int mt = 0; mt < 2; ++mt)
#pragma unroll
      for (int r = 0; r < 4; ++r) {
        float s = 0.f;
#pragma unroll
        for (int nt = 0; nt < 4; ++nt) s = fmaf(acc[mt][nt][r] + bb[nt], wv[nt], s);
        s += __shfl_xor(s, 1, 16); s += __shfl_xor(s, 2, 16);
        s += __shfl_xor(s, 4, 16); s += __shfl_xor(s, 8, 16);
        int i = bm + wm + mt * 16 + quad * 4 + r;
        if (l15 == 0 && i < S_) atomicAdd(&gp[rowbase + i], s);
      }
  } else {
    // v: LDS transpose (2-way conflicts = free) then coalesced aligned int4
    ushort_t* lt = &Bs[0][0];                    // 64d x 72i tile
    int ti = tid >> 2, tc = (tid & 3) * 16;
#pragma unroll
    for (int hh = 0; hh < 2; ++hh) {
      __syncthreads();
      if ((w >> 1) == hh) {
#pragma unroll
        for (int mt = 0; mt < 2; ++mt)
#pragma unroll
          for (int nt = 0; nt < 4; ++nt) {
            int d = nt * 16 + l15;
#pragma unroll
            for (int r = 0; r < 4; ++r) {
              int il = wm + mt * 16 + quad * 4 + r;
              lt[d * 72 + il] = f2bf(acc[mt][nt][r] + bb[nt]);
            }
          }
      }
      __syncthreads();
      int hg = (bn >> 6) + hh;
      union { int4 q[2]; ushort_t u[16]; } tv;
      tv.q[0] = *(const int4*)&lt[ti * 72 + tc];
      tv.q[1] = *(const int4*)&lt[ti * 72 + tc + 8];
      size_t vrow = ((size_t)(bg2 * H_ + hg) * 64 + ti) * SP_;
#pragma unroll
      for (int c8 = 0; c8 < 2; ++c8) {
        int i2 = bm + tc + c8 * 8;
        if (i2 + 7 < S_) {
          *(int4*)&vT[vrow + i2] = tv.q[c8];
        } else {
#pragma unroll
          for (int e = 0; e < 8; ++e)
            if (i2 + e < S_) vT[vrow + i2 + e] = tv.u[c8 * 8 + e];
        }
      }
    }
  }
}

// ---------------------------------------------------------------------------
// MFMA flash attention, S^T form, fixed-reference softmax, thirds split.
// K and V^T both staged in LDS (R8 structure — direct-V global reads span 64
// cache lines per instr and regressed 48->68 µs). exp2 + folded Q scale.
// LDS 30.7KB -> 5 blocks/CU; grid 1584.
// ---------------------------------------------------------------------------
__global__ __launch_bounds__(256) void attn_kernel(
    const ushort_t* __restrict__ qb, const ushort_t* __restrict__ kb,
    const ushort_t* __restrict__ vT, const float* __restrict__ gq_raw,
    const float* __restrict__ gk_raw, const float* __restrict__ bgate,
    float* __restrict__ Opart, float* __restrict__ Lpart)
{
  __shared__ __align__(16) ushort_t Ks[64][72];    // [j][d]
  __shared__ __align__(16) ushort_t Vt[64][72];    // [d][j]
  __shared__ __align__(16) ushort_t Ps[4][16][72]; // per-wave P [i][j]
  __shared__ float gbs[704];

  int tid = threadIdx.x;
  int lane = tid & 63, w = tid >> 6;
  int l15 = lane & 15, quad = lane >> 4;

  // middle-out q-tile order; 48 blocks (16 bh x 3 thirds) per qt
  int sub = blockIdx.x % 48;
  int qidx = blockIdx.x / 48;
  int off = (qidx + 1) >> 1;
  int qt = 16 + ((qidx & 1) ? -off : off);          // 0..32
  int bh = sub & 15, third = sub >> 4;
  int h = bh & 7, b = bh >> 3;
  int i0 = qt * 64;
  const float LOG2E = 1.44269504f;
  const float coef2 = (-0.5f / (512.f * 512.f)) * LOG2E;
  const float QSC = 0.125f * LOG2E;

  // per-thread q-row
  int i = i0 + w * 16 + l15;
  int ic = (i < S_) ? i : S_ - 1;
  bf16x8 qf0 = *(const bf16x8*)&qb[((size_t)(b * S_ + ic)) * E_ + h * 64 + quad * 8];
  bf16x8 qf1 = *(const bf16x8*)&qb[((size_t)(b * S_ + ic)) * E_ + h * 64 + 32 + quad * 8];
#pragma unroll
  for (int e = 0; e < 8; ++e) {                     // fold D^-0.5 * log2e into Q
    qf0[e] = (short)f2bf(bf2f((ushort_t)qf0[e]) * QSC);
    qf1[e] = (short)f2bf(bf2f((ushort_t)qf1[e]) * QSC);
  }
  float av = __expf(-(gq_raw[b * S_ + ic] + bgate[0]));
  float fdi = (i < S_) ? (float)i : -1e5f;

  int jlo = i0 - WIN_; if (jlo < 0) jlo = 0;
  int jt_lo = jlo >> 6;
  int jhi = i0 + 63 + WIN_; if (jhi > S_ - 1) jhi = S_ - 1;
  int jt_hi = jhi >> 6;
  int L = jt_hi - jt_lo + 1;                        // 17..33
  int n0 = (L + 2) / 3, n1 = (L + 1) / 3;
  int myLo = jt_lo + ((third == 0) ? 0 : (third == 1) ? n0 : n0 + n1);
  int cnt = (third == 0) ? n0 : (third == 1) ? n1 : L - n0 - n1;
  int myHi = myLo + cnt - 1;
  int jbase = myLo << 6;
  int nwin = cnt << 6;                              // <= 704

  for (int tt = tid; tt < nwin; tt += 256) {
    int j = jbase + tt; int jc = (j < S_) ? j : S_ - 1;
    gbs[tt] = __expf(-gk_raw[b * S_ + jc]);
  }

  // staging maps: K rows=j, V^T rows=d; both 64x64, 2 int4 per thread
  int srow = tid >> 2, scol = (tid & 3) * 16;
  const ushort_t* kb_base = kb + (size_t)b * S_ * E_ + h * 64 + scol;
  const ushort_t* vb_base = vT + ((size_t)(b * H_ + h) * 64 + srow) * SP_ + scol;

  int4 ka0, ka1, va0, va1;
  {
    int jc0 = jbase + srow; if (jc0 > S_ - 1) jc0 = S_ - 1;
    const int4* kp = (const int4*)(kb_base + (size_t)jc0 * E_);
    ka0 = kp[0]; ka1 = kp[1];
    const int4* vp = (const int4*)(vb_base + jbase);
    va0 = vp[0]; va1 = vp[1];
  }

  const f32x4 fz = {0.f, 0.f, 0.f, 0.f};
  f32x4 Ov[4] = {fz, fz, fz, fz};
  float l_run = 0.f;

  for (int jt = myLo; jt <= myHi; ++jt) {
    int j0 = jt << 6;
    __syncthreads();
    int jn = (jt < myHi) ? ((jt + 1) << 6) : j0;
    int jcn = jn + srow; if (jcn > S_ - 1) jcn = S_ - 1;
    const int4* kp = (const int4*)(kb_base + (size_t)jcn * E_);
    int4 nk0 = kp[0], nk1 = kp[1];
    const int4* vp = (const int4*)(vb_base + jn);
    int4 nv0 = vp[0], nv1 = vp[1];
    *(int4*)&Ks[srow][scol] = ka0; *(int4*)&Ks[srow][scol + 8] = ka1;
    *(int4*)&Vt[srow][scol] = va0; *(int4*)&Vt[srow][scol + 8] = va1;
    __syncthreads();

    // S^T = K . Q^T : lane holds one q-row (i=l15), 16 j's
    f32x4 st[4];
#pragma unroll
    for (int nt = 0; nt < 4; ++nt) {
      bf16x8 kf0 = *(const bf16x8*)&Ks[nt * 16 + l15][quad * 8];
      bf16x8 kf1 = *(const bf16x8*)&Ks[nt * 16 + l15][32 + quad * 8];
      f32x4 s = MFMA16(kf0, qf0, fz);
      st[nt] = MFMA16(kf1, qf1, s);
    }

    bool full = ((j0 + 63 - i0) <= WIN_) && ((i0 + 63 - j0) <= WIN_)
                && (j0 + 63 < S_) && (i0 + 63 < S_);
    float ps = 0.f;
    float fq = fdi - (float)(j0 + quad * 4);
    if (full) {
#pragma unroll
      for (int nt = 0; nt < 4; ++nt) {
        f32x4 g4 = *(const f32x4*)&gbs[(j0 - jbase) + nt * 16 + quad * 4];
#pragma unroll
        for (int r = 0; r < 4; ++r) {
          float f = fq - (float)(nt * 16 + r);
          float gate = __builtin_amdgcn_rcpf(fmaf(av, g4[r], 1.f));
          float p = __builtin_amdgcn_exp2f(fmaf(f * f, coef2, st[nt][r]) * gate);
          st[nt][r] = p; ps += p;
        }
      }
    } else {
#pragma unroll
      for (int nt = 0; nt < 4; ++nt) {
        f32x4 g4 = *(const f32x4*)&gbs[(j0 - jbase) + nt * 16 + quad * 4];
#pragma unroll
        for (int r = 0; r < 4; ++r) {
          int j = j0 + nt * 16 + quad * 4 + r;
          float fj = (j < S_) ? (float)j : 1e5f;
          float f = fdi - fj;
          float gate = __builtin_amdgcn_rcpf(fmaf(av, g4[r], 1.f));
          float t = fmaf(f * f, coef2, st[nt][r]) * gate;
          t = (__builtin_fabsf(f) <= 1024.f) ? t : -1e30f;
          float p = __builtin_amdgcn_exp2f(t);
          st[nt][r] = p; ps += p;
        }
      }
    }
    ps += __shfl_xor(ps, 16);
    ps += __shfl_xor(ps, 32);
    l_run += ps;

#pragma unroll
    for (int nt = 0; nt < 4; ++nt) {
      uint2 pk;
      pk.x = (unsigned int)f2bf(st[nt][0]) | ((unsigned int)f2bf(st[nt][1]) << 16);
      pk.y = (unsigned int)f2bf(st[nt][2]) | ((unsigned int)f2bf(st[nt][3]) << 16);
      *(uint2*)&Ps[w][l15][nt * 16 + quad * 4] = pk;
    }
    bf16x8 p0 = *(const bf16x8*)&Ps[w][l15][quad * 8];
    bf16x8 p1 = *(const bf16x8*)&Ps[w][l15][32 + quad * 8];
#pragma unroll
    for (int nt = 0; nt < 4; ++nt) {
      bf16x8 v0 = *(const bf16x8*)&Vt[nt * 16 + l15][quad * 8];
      bf16x8 v1 = *(const bf16x8*)&Vt[nt * 16 + l15][32 + quad * 8];
      Ov[nt] = MFMA16(p0, v0, Ov[nt]);
      Ov[nt] = MFMA16(p1, v1, Ov[nt]);
    }
    ka0 = nk0; ka1 = nk1; va0 = nv0; va1 = nv1;
  }

  // store unnormalized partials (fp32)
  if (lane < 16) {
    int irow = i0 + w * 16 + lane;
    if (irow < S_)
      Lpart[(size_t)third * BHS_ + (size_t)(b * H_ + h) * S_ + irow] = l_run;
  }
#pragma unroll
  for (int r = 0; r < 4; ++r) {
    int irow = i0 + w * 16 + quad * 4 + r;
    if (irow < S_) {
      size_t base = ((size_t)third * BHS_ + (size_t)(b * H_ + h) * S_ + irow) * 64;
#pragma unroll
      for (int nt = 0; nt < 4; ++nt)
        Opart[base + nt * 16 + l15] = Ov[nt][r];
    }
  }
}

// ---------------------------------------------------------------------------
// Combine thirds: o = (O1+O2+O3)/(l1+l2+l3); emit hi/lo bf16, row-major.
// ---------------------------------------------------------------------------
__global__ __launch_bounds__(256) void combine_kernel(
    const float* __restrict__ Opart, const float* __restrict__ Lpart,
    ushort_t* __restrict__ ahi, ushort_t* __restrict__ alo)
{
  int tid = threadIdx.x;
  int gi = blockIdx.x * 16 + (tid >> 4);            // [0, 32784)
  int d4 = tid & 15;
  int b = gi / (H_ * S_);
  int rem = gi - b * (H_ * S_);
  int h = rem / S_;
  int i = rem - h * S_;
  size_t p0 = (size_t)(b * H_ + h) * S_ + i;
  float l = Lpart[p0] + Lpart[p0 + (size_t)BHS_] + Lpart[p0 + 2 * (size_t)BHS_];
  float inv = 1.f / l;
  const float* op = Opart + p0 * 64 + d4 * 4;
  float4 o1 = *(const float4*)op;
  float4 o2 = *(const float4*)(op + (size_t)BHS_ * 64);
  float4 o3 = *(const float4*)(op + 2 * (size_t)BHS_ * 64);
  float o[4] = {(o1.x + o2.x + o3.x) * inv, (o1.y + o2.y + o3.y) * inv,
                (o1.z + o2.z + o3.z) * inv, (o1.w + o2.w + o3.w) * inv};
  ushort4 hi, lo;
  hi.x = f2bf(o[0]); lo.x = f2bf(o[0] - bf2f(hi.x));
  hi.y = f2bf(o[1]); lo.y = f2bf(o[1] - bf2f(hi.y));
  hi.z = f2bf(o[2]); lo.z = f2bf(o[2] - bf2f(hi.z));
  hi.w = f2bf(o[3]); lo.w = f2bf(o[3] - bf2f(hi.w));
  size_t oidx = ((size_t)b * S_ + i) * E_ + h * 64 + d4 * 4;
  *(ushort4*)&ahi[oidx] = hi;
  *(ushort4*)&alo[oidx] = lo;
}

// ---------------------------------------------------------------------------
// Output projection, 64x128 tile, 2x2 waves (32x64 each), 2-term split:
// C = (Ahi + Alo) @ Whi + bias (fp32 out). Grid (65,4), reg-prefetch.
// ---------------------------------------------------------------------------
__global__ __launch_bounds__(256) void gemm_out_kernel(
    const ushort_t* __restrict__ Ahi, const ushort_t* __restrict__ Alo,
    const ushort_t* __restrict__ Whi, const float* __restrict__ bias,
    float* __restrict__ C)
{
  __shared__ __align__(16) ushort_t AsH[64][40];
  __shared__ __align__(16) ushort_t AsL[64][40];
  __shared__ __align__(16) ushort_t BsW[128][40];
  int tid = threadIdx.x;
  int lane = tid & 63, w = tid >> 6;
  int l15 = lane & 15, quad = lane >> 4;
  int wm = (w & 1) * 32, wn = (w >> 1) * 64;
  int bm = blockIdx.x * 64, bn = blockIdx.y * 128;

  int sr = tid >> 2, sc = (tid & 3) * 8;
  int am = bm + sr; if (am >= MROWS) am = MROWS - 1;
  const ushort_t* ahp = Ahi + (size_t)am * E_ + sc;
  const ushort_t* alp = Alo + (size_t)am * E_ + sc;
  int br = tid >> 1, bc = (tid & 1) * 16;
  const ushort_t* bp = Whi + (size_t)(bn + br) * E_ + bc;

  const f32x4 fz = {0.f, 0.f, 0.f, 0.f};
  f32x4 acc[2][4];
#pragma unroll
  for (int mt = 0; mt < 2; ++mt)
#pragma unroll
    for (int nt = 0; nt < 4; ++nt) acc[mt][nt] = fz;

  int4 ph = *(const int4*)ahp, pl = *(const int4*)alp;
  int4 pb0 = *(const int4*)bp, pb1 = *(const int4*)(bp + 8);

  for (int k0 = 0; k0 < E_; k0 += 32) {
    __syncthreads();
    int kn = (k0 + 32 < E_) ? (k0 + 32) : k0;
    int4 nh = *(const int4*)(ahp + kn);
    int4 nl = *(const int4*)(alp + kn);
    int4 nb0 = *(const int4*)(bp + kn), nb1 = *(const int4*)(bp + kn + 8);
    *(int4*)&AsH[sr][sc] = ph;
    *(int4*)&AsL[sr][sc] = pl;
    *(int4*)&BsW[br][bc] = pb0; *(int4*)&BsW[br][bc + 8] = pb1;
    __syncthreads();
    bf16x8 ah[2], al[2], bw[4];
#pragma unroll
    for (int mt = 0; mt < 2; ++mt) {
      ah[mt] = *(const bf16x8*)&AsH[wm + mt * 16 + l15][quad * 8];
      al[mt] = *(const bf16x8*)&AsL[wm + mt * 16 + l15][quad * 8];
    }
#pragma unroll
    for (int nt = 0; nt < 4; ++nt) bw[nt] = *(const bf16x8*)&BsW[wn + nt * 16 + l15][quad * 8];
#pragma unroll
    for (int mt = 0; mt < 2; ++mt)
#pragma unroll
      for (int nt = 0; nt < 4; ++nt) {
        acc[mt][nt] = MFMA16(ah[mt], bw[nt], acc[mt][nt]);
        acc[mt][nt] = MFMA16(al[mt], bw[nt], acc[mt][nt]);
      }
    ph = nh; pl = nl; pb0 = nb0; pb1 = nb1;
  }
#pragma unroll
  for (int nt = 0; nt < 4; ++nt) {
    float bb = bias[bn + wn + nt * 16 + l15];
#pragma unroll
    for (int mt = 0; mt < 2; ++mt)
#pragma unroll
      for (int r = 0; r < 4; ++r) {
        int m = bm + wm + mt * 16 + quad * 4 + r;
        if (m < MROWS)
          C[(size_t)m * E_ + bn + wn + nt * 16 + l15] = acc[mt][nt][r] + bb;
      }
  }
}

// ---------------------------------------------------------------------------
extern "C" void kernel_launch(void* const* d_in, const int* in_sizes, int n_in,
                              void* d_out, int out_size, void* d_ws, size_t ws_size,
                              hipStream_t stream) {
  const float* x  = (const float*)d_in[0];
  const float* Wq = (const float*)d_in[1];
  const float* bq = (const float*)d_in[2];
  const float* Wk = (const float*)d_in[3];
  const float* bk = (const float*)d_in[4];
  const float* Wv = (const float*)d_in[5];
  const float* bv = (const float*)d_in[6];
  const float* Wo = (const float*)d_in[7];
  const float* bo = (const float*)d_in[8];
  const float* wg = (const float*)d_in[9];
  const float* bg = (const float*)d_in[10];

  char* p = (char*)d_ws;
  ushort_t* Wt_all = (ushort_t*)p; p += (size_t)3 * E_ * E_ * 2;         // 1.57 MB
  ushort_t* WoHi   = (ushort_t*)p; p += (size_t)E_ * E_ * 2;             // 0.52 MB
  ushort_t* qkb    = (ushort_t*)p; p += (size_t)2 * MROWS * E_ * 2;      // 8.39 MB
  ushort_t* vT     = (ushort_t*)p; p += (size_t)B_ * H_ * 64 * SP_ * 2;  // 4.46 MB
  float*    gacc   = (float*)p;    p += (size_t)2 * GBUFN * 4;           // 33 KB
  float*    Opart  = (float*)p;    p += (size_t)3 * BHS_ * 64 * 4;       // 25.2 MB
  float*    Lpart  = (float*)p;    p += (size_t)3 * BHS_ * 4;            // 0.39 MB
  // xb aliases Opart: xb is dead after qkv; Opart written only in attn.
  ushort_t* xb     = (ushort_t*)Opart;
  // aHi/aLo alias qkb: q/k are dead once attn completes (stream-ordered).
  ushort_t* aHi    = qkb;
  ushort_t* aLo    = qkb + (size_t)MROWS * E_;                           // ~40.6 MB

  hipLaunchKernelGGL(convert_all_kernel, dim3(3073), dim3(256), 0, stream,
                     x, Wq, Wk, Wv, Wo, xb, Wt_all, WoHi, gacc);
  hipLaunchKernelGGL(gemm_qkv_kernel, dim3(66, 4, 3), dim3(256), 0, stream,
                     xb, Wt_all, bq, bk, bv, wg, qkb, vT, gacc);
  hipLaunchKernelGGL(attn_kernel, dim3(33 * 48), dim3(256), 0, stream,
                     qkb, qkb + (size_t)MROWS * E_, vT, gacc, gacc + GBUFN, bg,
                     Opart, Lpart);
  hipLaunchKernelGGL(combine_kernel, dim3(2049), dim3(256), 0, stream,
                     Opart, Lpart, aHi, aLo);
  hipLaunchKernelGGL(gemm_out_kernel, dim3(65, 4), dim3(256), 0, stream,
                     aHi, aLo, WoHi, bo, (float*)d_out);
}